// Round 2
// baseline (293.631 us; speedup 1.0000x reference)
//
#include <hip/hip_runtime.h>
#include <math.h>

#define NT 16384
#define DIM 2048
#define NE 64
#define TK 8

typedef _Float16 f16_t;
typedef _Float16 half8 __attribute__((ext_vector_type(8)));
typedef float floatx16 __attribute__((ext_vector_type(16)));

// ---------------- Prep: W fp32 -> f16 hi/lo in 32x32x16 B-fragment order; block 64 = scalar chain ----------------
// B-frag layout (verified): lane holds B[n=lane&31][k=8*(lane>>5)+j], one 16B half8 per frag.
__global__ __launch_bounds__(256) void prep_kernel(const float* __restrict__ w,
                                                   const float* __restrict__ expert_loads,
                                                   const float* __restrict__ bias_strength,
                                                   float* __restrict__ ws_bias,
                                                   float* __restrict__ ws_batch,
                                                   unsigned int* __restrict__ ws_counter,
                                                   f16_t* __restrict__ whi,
                                                   f16_t* __restrict__ wlo,
                                                   float* __restrict__ out_bias_strength) {
    if (blockIdx.x == 64) {
        int e = threadIdx.x;
        if (e < 64) {
            float load = expert_loads[e];
            float s = load;
            #pragma unroll
            for (int off = 32; off >= 1; off >>= 1) s += __shfl_xor(s, off, 64);
            s = fmaxf(s, 1e-8f);
            float q = load / s;
            const float t = 1.0f / 64.0f;
            float kl = t * (logf(t) - logf(fmaxf(q, 1e-8f)));
            #pragma unroll
            for (int off = 32; off >= 1; off >>= 1) kl += __shfl_xor(kl, off, 64);
            float as = 1.0f / (1.0f + expf(-10.0f * kl));
            float nbs = 0.9f * bias_strength[0] + 0.1f * as;
            ws_bias[e] = tanhf((q - t) * 64.0f) * nbs;
            ws_batch[e] = 0.0f;
            if (e == 0) { out_bias_strength[0] = nbs; ws_counter[0] = 0u; }
        }
        return;
    }
    int idx = blockIdx.x * 256 + threadIdx.x;   // (c16, tile, lane)
    int lane = idx & 63;
    int tile = (idx >> 6) & 1;
    int c    = idx >> 7;
    int n = tile * 32 + (lane & 31);
    int k = c * 16 + (lane >> 5) * 8;
    const float* src = w + (size_t)n * DIM + k;
    float4 a = *(const float4*)src;
    float4 b = *(const float4*)(src + 4);
    float v[8] = {a.x, a.y, a.z, a.w, b.x, b.y, b.z, b.w};
    half8 h, l;
    #pragma unroll
    for (int j = 0; j < 8; ++j) {
        f16_t hh = (f16_t)v[j];
        h[j] = hh;
        l[j] = (f16_t)(v[j] - (float)hh);
    }
    *(half8*)(whi + (size_t)idx * 8) = h;
    *(half8*)(wlo + (size_t)idx * 8) = l;
}

// ---------------- Main: direct-to-register split-f16 MFMA GEMM + noise + bias + top-8 + softmax + fused EMA ----
// 512 thr = 8 waves = split-K x8 (wave wv owns k-chunks s*16 + wv*2 + {0,1}). Tile 32 tokens x 64 experts.
// NO K-loop LDS, NO K-loop barriers: A-fragment layout (row=L&31, col=c16*16+(L>>5)*8) is loaded straight
// from global. Lanes (L, L+32) x 4 dwordx4 per window cover one aligned 128B line per row, fully consumed
// in-iteration -> zero over-fetch. Depth-1 register prefetch (next window's A issued before this window's
// convert+MFMA); 16 waves/CU TLP hides the rest. LDS is epilogue-only (part[8][32][68]).
// FP order of the 6-MFMA hi/lo sequence, B-frag indices, C/D layout preserved bit-for-bit vs verified kernel.
__global__ __launch_bounds__(512, 4) void router_main(const float* __restrict__ x,
                                                      const f16_t* __restrict__ whi,
                                                      const f16_t* __restrict__ wlo,
                                                      const float* __restrict__ noise,
                                                      const float* __restrict__ ws_bias,
                                                      float* __restrict__ ws_batch,
                                                      unsigned int* __restrict__ ws_counter,
                                                      const float* __restrict__ expert_loads,
                                                      float* __restrict__ out) {
    __shared__ float smem[17408];     // part[8][32][68] f32 = 69,632 B (epilogue only)
    __shared__ float bias_sh[64];
    __shared__ float loads_sh[64];
    __shared__ int last_flag;

    const int tid = threadIdx.x;
    const int wv  = tid >> 6;        // 0..7: split-K partition
    const int L   = tid & 63;
    const int r   = L & 31;          // A-frag row (token within tile)
    const int kh  = L >> 5;
    const int token0 = blockIdx.x * 32;

    if (tid < 64) { bias_sh[tid] = ws_bias[tid]; loads_sh[tid] = 0.0f; }
    if (tid == 0) last_flag = 0;

    const half8* whi8 = (const half8*)whi;
    const half8* wlo8 = (const half8*)wlo;

    floatx16 acc0, acc1;
    #pragma unroll
    for (int i = 0; i < 16; ++i) { acc0[i] = 0.0f; acc1[i] = 0.0f; }

    // Per-lane A base: row (token0+r), col = wv*32 + kh*8; windows advance by 256 cols.
    const float* abase = x + (size_t)(token0 + r) * DIM + wv * 32 + kh * 8;

    // Prefetch window 0
    float4 pa0 = *(const float4*)(abase);
    float4 pa1 = *(const float4*)(abase + 4);
    float4 pa2 = *(const float4*)(abase + 16);
    float4 pa3 = *(const float4*)(abase + 20);

    #pragma unroll 1
    for (int s = 0; s < 8; ++s) {
        float4 a0 = pa0, a1 = pa1, a2 = pa2, a3 = pa3;   // consume window s (wait lands at convert)
        if (s < 7) {                                     // issue window s+1 early
            const float* nb = abase + (s + 1) * 256;
            pa0 = *(const float4*)(nb);
            pa1 = *(const float4*)(nb + 4);
            pa2 = *(const float4*)(nb + 16);
            pa3 = *(const float4*)(nb + 20);
        }
        // B fragments for this window's two chunks (L2-resident, 8 x 16B)
        const int c0 = s * 16 + wv * 2;
        const int i0 = (c0 * 2) * 64 + L;
        const int i1 = ((c0 + 1) * 2) * 64 + L;
        half8 b0h = whi8[i0], b1h = whi8[i0 + 64];
        half8 b0l = wlo8[i0], b1l = wlo8[i0 + 64];
        half8 b2h = whi8[i1], b3h = whi8[i1 + 64];
        half8 b2l = wlo8[i1], b3l = wlo8[i1 + 64];

        // chunk cc=0: cols [c0*16 + kh*8, +8)
        {
            float v[8] = {a0.x, a0.y, a0.z, a0.w, a1.x, a1.y, a1.z, a1.w};
            half8 ah, al;
            #pragma unroll
            for (int j = 0; j < 8; ++j) {
                f16_t hh = (f16_t)v[j];              // RNE hi (verified numerics)
                ah[j] = hh;
                al[j] = (f16_t)(v[j] - (float)hh);   // RNE lo
            }
            acc0 = __builtin_amdgcn_mfma_f32_32x32x16_f16(ah, b0h, acc0, 0, 0, 0);
            acc1 = __builtin_amdgcn_mfma_f32_32x32x16_f16(ah, b1h, acc1, 0, 0, 0);
            acc0 = __builtin_amdgcn_mfma_f32_32x32x16_f16(al, b0h, acc0, 0, 0, 0);
            acc1 = __builtin_amdgcn_mfma_f32_32x32x16_f16(al, b1h, acc1, 0, 0, 0);
            acc0 = __builtin_amdgcn_mfma_f32_32x32x16_f16(ah, b0l, acc0, 0, 0, 0);
            acc1 = __builtin_amdgcn_mfma_f32_32x32x16_f16(ah, b1l, acc1, 0, 0, 0);
        }
        // chunk cc=1: cols +16
        {
            float v[8] = {a2.x, a2.y, a2.z, a2.w, a3.x, a3.y, a3.z, a3.w};
            half8 ah, al;
            #pragma unroll
            for (int j = 0; j < 8; ++j) {
                f16_t hh = (f16_t)v[j];
                ah[j] = hh;
                al[j] = (f16_t)(v[j] - (float)hh);
            }
            acc0 = __builtin_amdgcn_mfma_f32_32x32x16_f16(ah, b2h, acc0, 0, 0, 0);
            acc1 = __builtin_amdgcn_mfma_f32_32x32x16_f16(ah, b3h, acc1, 0, 0, 0);
            acc0 = __builtin_amdgcn_mfma_f32_32x32x16_f16(al, b2h, acc0, 0, 0, 0);
            acc1 = __builtin_amdgcn_mfma_f32_32x32x16_f16(al, b3h, acc1, 0, 0, 0);
            acc0 = __builtin_amdgcn_mfma_f32_32x32x16_f16(ah, b2l, acc0, 0, 0, 0);
            acc1 = __builtin_amdgcn_mfma_f32_32x32x16_f16(ah, b3l, acc1, 0, 0, 0);
        }
    }

    // C/D layout (verified m74/m101): col=lane&31, row=(reg&3)+8*(reg>>2)+4*kh
    // smem untouched during GEMM -> no barrier needed before the part[] writes.
    #pragma unroll
    for (int reg = 0; reg < 16; ++reg) {
        int row = (reg & 3) + 8 * (reg >> 2) + 4 * kh;
        smem[wv * 2176 + row * 68 + r]      = acc0[reg];
        smem[wv * 2176 + row * 68 + 32 + r] = acc1[reg];
    }
    __syncthreads();

    // Split-K reduce + noise + bias -> final logits into part[0]
    #pragma unroll
    for (int p = 0; p < 4; ++p) {
        int o = tid + p * 512;               // 0..2047
        int t = o >> 6, e = o & 63;
        float sum = 0.0f;
        #pragma unroll
        for (int q = 0; q < 8; ++q) sum += smem[q * 2176 + t * 68 + e];
        sum += noise[(size_t)(token0 + t) * NE + e] * 0.01f - bias_sh[e];
        smem[t * 68 + e] = sum;              // own slot; no cross-thread hazard
    }
    __syncthreads();

    // Top-8 (strict '>' keeps lower index on ties, matching jax.lax.top_k) + softmax + load scatter
    if (tid < 32) {
        int t = tid;
        float tv[TK]; int ti_[TK];
        #pragma unroll
        for (int j = 0; j < TK; ++j) { tv[j] = -INFINITY; ti_[j] = 0; }
        for (int e = 0; e < NE; ++e) {
            float v = smem[t * 68 + e]; int id = e;
            #pragma unroll
            for (int j = 0; j < TK; ++j) {
                bool gt = v > tv[j];
                float nv = gt ? v : tv[j];
                int   ni = gt ? id : ti_[j];
                float ov = gt ? tv[j] : v;
                int   oi = gt ? ti_[j] : id;
                tv[j] = nv; ti_[j] = ni; v = ov; id = oi;
            }
        }
        float m = tv[0], ssum = 0.0f, wvv[TK];
        #pragma unroll
        for (int j = 0; j < TK; ++j) { wvv[j] = expf(tv[j] - m); ssum += wvv[j]; }
        float inv = 1.0f / ssum;
        size_t gt_ = (size_t)(token0 + t);
        #pragma unroll
        for (int j = 0; j < TK; ++j) {
            float wgt = wvv[j] * inv;
            out[gt_ * TK + j] = (float)ti_[j];
            out[(size_t)NT * TK + gt_ * TK + j] = wgt;
            atomicAdd(&loads_sh[ti_[j]], wgt);
        }
    }
    __syncthreads();
    if (tid < 64) atomicAdd(&ws_batch[tid], loads_sh[tid]);

    // ---- fused EMA finalize: last block to finish does it (device-scope counter) ----
    __threadfence();                          // ws_batch adds visible device-wide before counter bump
    if (tid == 0) {
        unsigned int prev = atomicAdd(ws_counter, 1u);
        if (prev == (unsigned int)(NT / 32 - 1)) last_flag = 1;
    }
    __syncthreads();
    if (last_flag && tid < 64) {
        float bl = atomicAdd(&ws_batch[tid], 0.0f);   // coherent read (cross-XCD safe)
        out[(size_t)NT * TK * 2 + tid] = 0.999f * expert_loads[tid] + 0.001f * (bl / (float)NT);
    }
}

extern "C" void kernel_launch(void* const* d_in, const int* in_sizes, int n_in,
                              void* d_out, int out_size, void* d_ws, size_t ws_size,
                              hipStream_t stream) {
    const float* x     = (const float*)d_in[0];  // [16384, 2048]
    const float* rw    = (const float*)d_in[1];  // [64, 2048]
    const float* loads = (const float*)d_in[2];  // [64]
    const float* bs    = (const float*)d_in[3];  // [1]
    const float* noise = (const float*)d_in[4];  // [16384, 64]
    float* out = (float*)d_out;                  // [131072 idx | 131072 w | 64 loads | 1 bias]
    float* ws  = (float*)d_ws;
    float* ws_bias  = ws;                        // [64]
    float* ws_batch = ws + 64;                   // [64]
    unsigned int* ws_counter = (unsigned int*)(ws + 128);
    f16_t* whi = (f16_t*)(ws + 160);             // 16384 frags x 8 halves = 256 KB (16B aligned)
    f16_t* wlo = whi + (size_t)16384 * 8;        // another 256 KB

    prep_kernel<<<65, 256, 0, stream>>>(rw, loads, bs, ws_bias, ws_batch, ws_counter, whi, wlo,
                                        out + (size_t)NT * TK * 2 + NE);
    router_main<<<NT / 32, 512, 0, stream>>>(x, whi, wlo, noise, ws_bias, ws_batch, ws_counter,
                                             loads, out);
}